// Round 6
// baseline (481.459 us; speedup 1.0000x reference)
//
#include <hip/hip_runtime.h>
#include <hip/hip_bf16.h>
#include <math.h>

// Problem constants (from reference): B=4, T=4096, D=1024, hidden=4D.
#define B_SZ 4
#define T_SZ 4096
#define D_SZ 1024
#define H_SZ 4096
#define CHUNK 16
#define NCHUNK (T_SZ / CHUNK)   // 256
#define NSEG 8
#define SEGC (NCHUNK / NSEG)    // 32 chunks per segment
#define LN_EPS 1e-5f

using frag8 = __attribute__((ext_vector_type(8))) short;   // 8 x bf16 (4 VGPRs)
using f32x4 = __attribute__((ext_vector_type(4))) float;   // 4 x f32 acc

__device__ __forceinline__ float gelu_exact(float x) {
  return 0.5f * x * (1.0f + erff(x * 0.70710678118654752f));
}

// tanh-form gelu: x*sigmoid(2u) = x - x/(e^{2u}+1), overflow-safe.
__device__ __forceinline__ float gelu_fast(float x) {
  float u2 = 1.5957691216057308f * (x + 0.044715f * x * x * x);
  float e = __expf(u2);
  return x - x * __builtin_amdgcn_rcpf(e + 1.0f);
}

__device__ __forceinline__ unsigned short f2bf(float f) {
  unsigned u = __float_as_uint(f);
  u += 0x7fffu + ((u >> 16) & 1u);   // round-to-nearest-even
  return (unsigned short)(u >> 16);
}

// ---------------------------------------------------------------------------
// Kernel A (LN1 stats fused in): per (b, time-chunk): per-row block reduction
// for mu/rstd, then LN1 + gelu + in-chunk cumsum. x is read exactly once.
// ---------------------------------------------------------------------------
__global__ __launch_bounds__(256) void attn_phase1(
    const float* __restrict__ x, const int* __restrict__ lengths,
    const float* __restrict__ w1, float* __restrict__ partial,
    float* __restrict__ csum) {
  __shared__ float red[8];
  int b = blockIdx.x >> 8;          // NCHUNK = 256
  int c = blockIdx.x & (NCHUNK - 1);
  int tid = threadIdx.x;
  int len = lengths[b];
  float4 w = ((const float4*)w1)[tid];
  float run0 = 0.f, run1 = 0.f, run2 = 0.f, run3 = 0.f;
  for (int i = 0; i < CHUNK; ++i) {
    int t = c * CHUNK + i;
    size_t row = ((size_t)b * T_SZ + t) * D_SZ;
    float4 v = ((const float4*)(x + row))[tid];
    float s = v.x + v.y + v.z + v.w;
    float q = v.x * v.x + v.y * v.y + v.z * v.z + v.w * v.w;
#pragma unroll
    for (int o = 32; o > 0; o >>= 1) {
      s += __shfl_xor(s, o, 64);
      q += __shfl_xor(q, o, 64);
    }
    if ((tid & 63) == 0) { red[(tid >> 6) * 2] = s; red[(tid >> 6) * 2 + 1] = q; }
    __syncthreads();
    s = red[0] + red[2] + red[4] + red[6];
    q = red[1] + red[3] + red[5] + red[7];
    __syncthreads();   // red reusable next row
    float mu = s * (1.0f / D_SZ);
    float var = q * (1.0f / D_SZ) - mu * mu;
    float rstd = rsqrtf(var + LN_EPS);
    bool valid = t < len;
    float hx = (v.x - mu) * rstd * w.x, hy = (v.y - mu) * rstd * w.y;
    float hz = (v.z - mu) * rstd * w.z, hw = (v.w - mu) * rstd * w.w;
    if (valid) {
      run0 += gelu_exact(hx); run1 += gelu_exact(hy);
      run2 += gelu_exact(hz); run3 += gelu_exact(hw);
    }
    float4 p;
    p.x = v.x + hx + (valid ? run0 : 0.f);
    p.y = v.y + hy + (valid ? run1 : 0.f);
    p.z = v.z + hz + (valid ? run2 : 0.f);
    p.w = v.w + hw + (valid ? run3 : 0.f);
    ((float4*)(partial + row))[tid] = p;
  }
  float4 cs; cs.x = run0; cs.y = run1; cs.z = run2; cs.w = run3;
  ((float4*)(csum + ((size_t)b * NCHUNK + c) * D_SZ))[tid] = cs;
}

// ---------------------------------------------------------------------------
// Kernel B1: per (b,seg,dq): in-place exclusive scan of 32 chunk sums within
// the segment + write segment total. Cross-segment offset applied in phase2.
// ---------------------------------------------------------------------------
__global__ __launch_bounds__(256) void seg_scan(float* __restrict__ csum,
                                                float* __restrict__ segsum) {
  int blk = blockIdx.x;   // b*32 + seg*4 + dq
  int b = blk >> 5, seg = (blk >> 2) & 7, dq = blk & 3;
  int d = dq * 256 + threadIdx.x;
  float* p = csum + ((size_t)b * NCHUNK + seg * SEGC) * D_SZ + d;
  float acc = 0.f;
#pragma unroll 8
  for (int j = 0; j < SEGC; ++j) {
    float v = p[(size_t)j * D_SZ];
    p[(size_t)j * D_SZ] = acc;
    acc += v;
  }
  segsum[((size_t)b * NSEG + seg) * D_SZ + d] = acc;
}

// ---------------------------------------------------------------------------
// Kernel C: xres = partial + valid*(csum + cross-seg offset) (in place),
// then LN2 -> h2 (bf16). seg_apply folded in (reads segsum directly).
// ---------------------------------------------------------------------------
__global__ __launch_bounds__(256) void attn_phase2_ln2(
    float* __restrict__ xres, const float* __restrict__ csum,
    const float* __restrict__ segsum, const int* __restrict__ lengths,
    const float* __restrict__ w2, unsigned short* __restrict__ h2) {
  __shared__ float red[8];
  int t = blockIdx.x & (T_SZ - 1);
  int b = blockIdx.x >> 12;
  int tid = threadIdx.x;
  bool valid = t < lengths[b];
  int c = t / CHUNK;
  int seg = c >> 5;   // SEGC = 32
  size_t row = ((size_t)b * T_SZ + t) * D_SZ;
  float4 v = ((const float4*)(xres + row))[tid];
  if (valid) {
    float4 o = ((const float4*)(csum + ((size_t)b * NCHUNK + c) * D_SZ))[tid];
    for (int s = 0; s < seg; ++s) {
      float4 g = ((const float4*)(segsum + ((size_t)b * NSEG + s) * D_SZ))[tid];
      o.x += g.x; o.y += g.y; o.z += g.z; o.w += g.w;
    }
    v.x += o.x; v.y += o.y; v.z += o.z; v.w += o.w;
  }
  ((float4*)(xres + row))[tid] = v;
  float s = v.x + v.y + v.z + v.w;
  float q = v.x * v.x + v.y * v.y + v.z * v.z + v.w * v.w;
#pragma unroll
  for (int o = 32; o > 0; o >>= 1) {
    s += __shfl_xor(s, o, 64);
    q += __shfl_xor(q, o, 64);
  }
  int wv = tid >> 6;
  if ((tid & 63) == 0) { red[wv * 2] = s; red[wv * 2 + 1] = q; }
  __syncthreads();
  s = red[0] + red[2] + red[4] + red[6];
  q = red[1] + red[3] + red[5] + red[7];
  float mu = s * (1.0f / D_SZ);
  float var = q * (1.0f / D_SZ) - mu * mu;
  float rstd = rsqrtf(var + LN_EPS);
  float4 w = ((const float4*)w2)[tid];
  ushort4 hq;
  hq.x = f2bf((v.x - mu) * rstd * w.x);
  hq.y = f2bf((v.y - mu) * rstd * w.y);
  hq.z = f2bf((v.z - mu) * rstd * w.z);
  hq.w = f2bf((v.w - mu) * rstd * w.w);
  ((ushort4*)(h2 + row))[tid] = hq;
}

// ---------------------------------------------------------------------------
// Transpose + fp32->bf16 convert: src (R x C) row-major -> dst (C x R) bf16.
// ---------------------------------------------------------------------------
__global__ __launch_bounds__(256) void transpose_f32_to_bf16(
    const float* __restrict__ src, unsigned short* __restrict__ dst,
    int R, int C) {
  __shared__ float tile[32][33];
  int bx = blockIdx.x * 32;   // C base
  int by = blockIdx.y * 32;   // R base
  int tx = threadIdx.x & 31;
  int ty = threadIdx.x >> 5;  // 0..7
#pragma unroll
  for (int i = 0; i < 32; i += 8)
    tile[ty + i][tx] = src[(size_t)(by + ty + i) * C + bx + tx];
  __syncthreads();
#pragma unroll
  for (int i = 0; i < 32; i += 8)
    dst[(size_t)(bx + ty + i) * R + by + tx] = f2bf(tile[tx][ty + i]);
}

// ---------------------------------------------------------------------------
// 128x128 bf16 GEMM, 2-blocks/CU TLP structure (round 6).
//   Rationale: rounds 1-5 (256^2 tile, 128 KiB LDS, 1 block/CU) pinned at
//   ~37% MfmaUtil across 3 schedules — lockstep waves expose every stall.
//   This kernel halves the tile so TWO independent blocks co-reside per CU
//   (64 KiB LDS each, ~150 regs/thread); the other block's MFMAs fill our
//   barrier/drain windows (m114 mechanism; m97's 912 TF came from TLP).
//   C[rows,N] = A[rows,K] * Bt[N,K]^T; 256 thr = 4 waves (2x2), wave tile
//   64x64, BK=64, dbuf, counted vmcnt(8) 2-ahead prefetch.
//   T2 swizzle (identical involution to r5): 16B chunk ^= (row&7), inverse
//   on global src of global_load_lds, forward on ds_read. Conflict-free.
//   LDS map (bytes): A buf0 [0,16K) buf1 [16K,32K); B buf0 [32K,48K)
//   buf1 [48K,64K). Row stride 128 B.
// ---------------------------------------------------------------------------
#define GLD16(gsrc, ldsoff)                                                   \
  __builtin_amdgcn_global_load_lds(                                           \
      (const __attribute__((address_space(1))) unsigned int*)(gsrc),          \
      (__attribute__((address_space(3))) unsigned int*)(smc + (ldsoff)), 16,  \
      0, 0)

// Stage one 128x64 tile (A or B): 4 x global_load_lds, rows tid>>3 + 32j,
// LDS dest linear (lane-contiguous 1024B per wave per j).
#define STAGE_A(P, k0e)                                                       \
  do {                                                                        \
    GLD16(gA + (size_t)0 * K + (k0e), aW + 0 + (P));                          \
    GLD16(gA + (size_t)32 * K + (k0e), aW + 4096 + (P));                      \
    GLD16(gA + (size_t)64 * K + (k0e), aW + 8192 + (P));                      \
    GLD16(gA + (size_t)96 * K + (k0e), aW + 12288 + (P));                     \
  } while (0)

#define STAGE_B(P, k0e)                                                       \
  do {                                                                        \
    GLD16(gB + (size_t)0 * K + (k0e), bW + 0 + (P));                          \
    GLD16(gB + (size_t)32 * K + (k0e), bW + 4096 + (P));                      \
    GLD16(gB + (size_t)64 * K + (k0e), bW + 8192 + (P));                      \
    GLD16(gB + (size_t)96 * K + (k0e), bW + 12288 + (P));                     \
  } while (0)

// A fragments: row = wm*64 + tm*16 + r16, byte = row*128 + ((kk*64+quad*16)
// ^ ((r16&7)<<4)). Bases aB0/aB1 hold everything but tm*2048 + parity.
template <int P>
__device__ __forceinline__ void rd_af(const char* smc, int aB0, int aB1,
                                      frag8 (&af)[4][2]) {
#pragma unroll
  for (int tm = 0; tm < 4; ++tm) {
    af[tm][0] = *(const frag8*)(smc + aB0 + (P + tm * 2048));
    af[tm][1] = *(const frag8*)(smc + aB1 + (P + tm * 2048));
  }
}

template <int P>
__device__ __forceinline__ void rd_bf(const char* smc, int bB0, int bB1,
                                      frag8 (&bf)[4][2]) {
#pragma unroll
  for (int tn = 0; tn < 4; ++tn) {
    bf[tn][0] = *(const frag8*)(smc + bB0 + (P + tn * 2048));
    bf[tn][1] = *(const frag8*)(smc + bB1 + (P + tn * 2048));
  }
}

// Raw barrier (no implicit vmcnt/lgkm drain) + compiler fence both sides.
#define GBAR()                          \
  do {                                  \
    asm volatile("" ::: "memory");      \
    __builtin_amdgcn_s_barrier();       \
    asm volatile("" ::: "memory");      \
  } while (0)

// One K-tile. P = parity byte offset (0/16384), compile-time.
//   rd 16 frags -> lgkmcnt(0) (this wave's reads drained) -> barrier (ALL
//   waves drained; buf[P] dead) -> stage t+2 into buf[P] -> 32 MFMA ->
//   vmcnt(8) completes tile t+1 (t+2's 8 stay in flight) -> barrier.
#define TILE_BODY(t, P)                                                       \
  do {                                                                        \
    bool p1 = (t) + 1 < nt, p2 = (t) + 2 < nt;                                \
    rd_af<P>(smc, aB0, aB1, af);                                              \
    rd_bf<P>(smc, bB0, bB1, bf);                                              \
    asm volatile("s_waitcnt lgkmcnt(0)" ::: "memory");                        \
    GBAR();                                                                   \
    if (p2) {                                                                 \
      STAGE_A(P, ((t) + 2) * 64);                                             \
      STAGE_B(P, ((t) + 2) * 64);                                             \
    }                                                                         \
    __builtin_amdgcn_s_setprio(1);                                            \
    _Pragma("unroll") for (int kk = 0; kk < 2; ++kk)                          \
        _Pragma("unroll") for (int tm = 0; tm < 4; ++tm)                      \
            _Pragma("unroll") for (int tn = 0; tn < 4; ++tn)                  \
                acc[tm][tn] = __builtin_amdgcn_mfma_f32_16x16x32_bf16(        \
                    af[tm][kk], bf[tn][kk], acc[tm][tn], 0, 0, 0);            \
    __builtin_amdgcn_s_setprio(0);                                            \
    if (p2 && p1)                                                             \
      asm volatile("s_waitcnt vmcnt(8)" ::: "memory");                        \
    else                                                                      \
      asm volatile("s_waitcnt vmcnt(0)" ::: "memory");                        \
    GBAR();                                                                   \
  } while (0)

__global__ __launch_bounds__(256, 2) void gemm128_bt(
    const unsigned short* __restrict__ A, const unsigned short* __restrict__ Bt,
    int N, int K, int gx,
    const float* __restrict__ resid, float* __restrict__ outf,
    unsigned short* __restrict__ outb, int epi) {
  extern __shared__ char smc[];   // 64 KiB

  // XCD-aware bijective block swizzle (grid % 8 == 0 in our launches).
  int orig = blockIdx.x, nwg = gridDim.x;
  int wg = orig;
  if ((nwg & 7) == 0) wg = (orig & 7) * (nwg >> 3) + (orig >> 3);
  int bx = wg % gx, by = wg / gx;
  int bm = by * 128, bn = bx * 128;

  int tid = threadIdx.x;
  int lane = tid & 63, wave = tid >> 6;
  int wm = wave >> 1, wn = wave & 1;         // 2 x 2 wave grid
  int quad = lane >> 4, r16 = lane & 15;

  const unsigned short* A_blk = A + (size_t)bm * K;
  const unsigned short* B_blk = Bt + (size_t)bn * K;
  int nt = K >> 6;   // 16 or 64 (even)

  // ---- LDS read bases (bytes), loop-invariant.
  int swz = (r16 & 7) << 4;
  int aB0 = (wm * 64 + r16) * 128 + ((quad * 16) ^ swz);
  int aB1 = (wm * 64 + r16) * 128 + ((64 + quad * 16) ^ swz);
  int bB0 = 32768 + (wn * 64 + r16) * 128 + ((quad * 16) ^ swz);
  int bB1 = 32768 + (wn * 64 + r16) * 128 + ((64 + quad * 16) ^ swz);

  // ---- staging bases, loop-invariant. Global k pre-swizzled (involution
  // with the read-side XOR; rows step by 32 so row&7 is per-thread const).
  int arow = tid >> 3;                                  // 0..31
  int kc = ((tid & 7) * 8) ^ ((arow & 7) << 3);         // elements
  const unsigned short* gA = A_blk + (size_t)arow * K + kc;
  const unsigned short* gB = B_blk + (size_t)arow * K + kc;
  int aW = arow * 128 + (tid & 7) * 16;                 // LDS dest bytes
  int bW = 32768 + arow * 128 + (tid & 7) * 16;

  f32x4 acc[4][4] = {};
  frag8 af[4][2], bf[4][2];

  // Prologue: stage tile0 + tile1 (8+8 loads); vmcnt(8) completes tile0.
  STAGE_A(0, 0);
  STAGE_B(0, 0);
  if (nt > 1) {
    STAGE_A(16384, 64);
    STAGE_B(16384, 64);
    asm volatile("s_waitcnt vmcnt(8)" ::: "memory");
  } else {
    asm volatile("s_waitcnt vmcnt(0)" ::: "memory");
  }
  GBAR();

  // Steady state: at tile-t start, tile t resident, t+1's 8 loads in flight.
  // Tile t issues t+2's 8 after the read-drain barrier; vmcnt(8) completes
  // exactly tile t+1. Unroll x2 -> parity is a compile-time immediate.
  for (int t = 0; t < nt; t += 2) {
    TILE_BODY(t, 0);
    TILE_BODY(t + 1, 16384);
  }

  // Epilogue. C row = bm + wm*64 + tm*16 + quad*4 + r; col = bn + wn*64 +
  // tn*16 + r16 (C/D layout: col=lane&15, row=(lane>>4)*4+reg).
  if (epi == 0) {
#pragma unroll
    for (int tm = 0; tm < 4; ++tm) {
#pragma unroll
      for (int tn = 0; tn < 4; ++tn) {
        int gm0 = bm + wm * 64 + tm * 16 + quad * 4;
        int gn = bn + wn * 64 + tn * 16 + r16;
#pragma unroll
        for (int r = 0; r < 4; ++r)
          outb[(size_t)(gm0 + r) * N + gn] = f2bf(gelu_fast(acc[tm][tn][r]));
      }
    }
  } else {
#pragma unroll
    for (int tm = 0; tm < 4; ++tm) {
#pragma unroll
      for (int tn = 0; tn < 4; ++tn) {
        int gm0 = bm + wm * 64 + tm * 16 + quad * 4;
        int gn = bn + wn * 64 + tn * 16 + r16;
#pragma unroll
        for (int r = 0; r < 4; ++r)
          outf[(size_t)(gm0 + r) * N + gn] =
              resid[(size_t)(gm0 + r) * N + gn] + acc[tm][tn][r];
      }
    }
  }
}

// ---------------------------------------------------------------------------
extern "C" void kernel_launch(void* const* d_in, const int* in_sizes, int n_in,
                              void* d_out, int out_size, void* d_ws,
                              size_t ws_size, hipStream_t stream) {
  const float* x = (const float*)d_in[0];
  const int* lengths = (const int*)d_in[1];
  const float* ln1_w = (const float*)d_in[2];
  const float* ln2_w = (const float*)d_in[3];
  const float* Wfc = (const float*)d_in[4];
  const float* Wproj = (const float*)d_in[5];
  float* out = (float*)d_out;   // doubles as the xres residual-stream buffer

  // One-time: allow 64 KiB dynamic LDS for the 128^2 GEMM (2 blocks/CU).
  static bool lds_cfg = false;
  if (!lds_cfg) {
    hipFuncSetAttribute((const void*)gemm128_bt,
                        hipFuncAttributeMaxDynamicSharedMemorySize, 65536);
    lds_cfg = true;
  }

  // Workspace layout — fixed ~52 MiB + act slice sized from ws_size.
  char* ws = (char*)d_ws;
  size_t off = 0;
  float* segsum = (float*)(ws + off);
  off += (size_t)B_SZ * NSEG * D_SZ * sizeof(float);            // 128 KiB
  float* csum = (float*)(ws + off);
  off += (size_t)B_SZ * NCHUNK * D_SZ * sizeof(float);          // 4 MiB
  unsigned short* wfcb = (unsigned short*)(ws + off);
  off += (size_t)D_SZ * H_SZ * sizeof(unsigned short);          // 8 MiB
  unsigned short* wprojb = (unsigned short*)(ws + off);
  off += (size_t)H_SZ * D_SZ * sizeof(unsigned short);          // 8 MiB
  unsigned short* h2 = (unsigned short*)(ws + off);
  off += (size_t)B_SZ * T_SZ * D_SZ * sizeof(unsigned short);   // 32 MiB
  unsigned short* act = (unsigned short*)(ws + off);            // slice buffer

  const int M = B_SZ * T_SZ;                       // 16384
  const size_t tileBytes = 256ull * H_SZ * sizeof(unsigned short);  // 2 MiB
  size_t avail = (ws_size > off) ? (ws_size - off) : 0;
  int sliceTiles = (int)(avail / tileBytes);
  if (sliceTiles < 1) sliceTiles = 1;              // last-resort (ws too small)
  int sliceM = sliceTiles * 256;
  if (sliceM > M) sliceM = M;

  attn_phase1<<<B_SZ * NCHUNK, 256, 0, stream>>>(x, lengths, ln1_w, out, csum);
  seg_scan<<<B_SZ * NSEG * (D_SZ / 256), 256, 0, stream>>>(csum, segsum);
  attn_phase2_ln2<<<B_SZ * T_SZ, 256, 0, stream>>>(out, csum, segsum, lengths,
                                                   ln2_w, h2);
  transpose_f32_to_bf16<<<dim3(H_SZ / 32, D_SZ / 32), 256, 0, stream>>>(
      Wfc, wfcb, D_SZ, H_SZ);
  transpose_f32_to_bf16<<<dim3(D_SZ / 32, H_SZ / 32), 256, 0, stream>>>(
      Wproj, wprojb, H_SZ, D_SZ);

  for (int m0 = 0; m0 < M; m0 += sliceM) {
    int rows = (M - m0 < sliceM) ? (M - m0) : sliceM;
    int rb = rows / 128;
    // act = bf16(gelu(h2[m0:m0+rows] @ Wfc))       grid = 32*rb (%8==0)
    gemm128_bt<<<dim3((H_SZ / 128) * rb), 256, 65536, stream>>>(
        h2 + (size_t)m0 * D_SZ, wfcb, H_SZ, D_SZ, H_SZ / 128,
        nullptr, nullptr, act, 0);
    // out[m0:m0+rows] += act @ Wproj               grid = 8*rb
    gemm128_bt<<<dim3((D_SZ / 128) * rb), 256, 65536, stream>>>(
        act, wprojb, D_SZ, H_SZ, D_SZ / 128,
        out + (size_t)m0 * D_SZ, out + (size_t)m0 * D_SZ, nullptr, 1);
  }
}